// Round 14
// baseline (620.760 us; speedup 1.0000x reference)
//
#include <hip/hip_runtime.h>
#include <cstdint>

#define DIMD  1024
#define NEXP  8
#define HIDN  4096
#define BATCH 4
#define SEQ   2048
#define CAPC  513                  // int(2048*2.0/8)+1
#define RPEX  2176                 // rows per expert, padded to 17*128
#define TPEX  17                   // 128-row tiles per expert
#define MTOT  (NEXP * RPEX)        // 17408
#define MTILES (MTOT / 128)        // 136

typedef __bf16 bf16x8 __attribute__((ext_vector_type(8)));
typedef float  f32x4  __attribute__((ext_vector_type(4)));

__device__ __forceinline__ unsigned short f2bf(float f) {
    unsigned u = __float_as_uint(f);
    unsigned r = (u + 0x7FFFu + ((u >> 16) & 1u)) >> 16;
    return (unsigned short)r;
}

// async 16B global->LDS (direct DMA). LDS dest = wave-uniform base + lane*16.
__device__ __forceinline__ void gl16(const unsigned short* g, unsigned short* l) {
    __builtin_amdgcn_global_load_lds(
        (const __attribute__((address_space(1))) void*)g,
        (__attribute__((address_space(3))) void*)l, 16, 0, 0);
}

// Within-XCD supercolumn traversal (128-row tiles). Grid = MTILES * nY.
__device__ __forceinline__ void swz_grp(int GY, int& bx, int& by) {
    int xcd = blockIdx.x & 7, pos = blockIdx.x >> 3;
    int tps = TPEX * GY;
    int sc = pos / tps, rem = pos - sc * tps;
    int bxl = rem / GY, byIn = rem - bxl * GY;
    bx = xcd * TPEX + bxl;
    by = sc * GY + byIn;
}

// ---------------- router: scores_t [B][E][S] = softmax over E ----------------
__global__ __launch_bounds__(64)
void router_kernel(const float* __restrict__ x, const float* __restrict__ rw,
                   float* __restrict__ scores) {
    int token = blockIdx.x;
    int lane  = threadIdx.x;
    const float4* xr = reinterpret_cast<const float4*>(x + (size_t)token * DIMD);
    float4 xv[4];
#pragma unroll
    for (int j = 0; j < 4; ++j) xv[j] = xr[lane * 4 + j];
    float acc[NEXP];
#pragma unroll
    for (int e = 0; e < NEXP; ++e) {
        const float4* wr = reinterpret_cast<const float4*>(rw + (size_t)e * DIMD);
        float a = 0.f;
#pragma unroll
        for (int j = 0; j < 4; ++j) {
            float4 wv = wr[lane * 4 + j];
            a += xv[j].x * wv.x; a += xv[j].y * wv.y;
            a += xv[j].z * wv.z; a += xv[j].w * wv.w;
        }
#pragma unroll
        for (int off = 32; off > 0; off >>= 1) a += __shfl_xor(a, off);
        acc[e] = a;
    }
    float m = acc[0];
#pragma unroll
    for (int e = 1; e < NEXP; ++e) m = fmaxf(m, acc[e]);
    float s = 0.f;
#pragma unroll
    for (int e = 0; e < NEXP; ++e) { acc[e] = expf(acc[e] - m); s += acc[e]; }
    float inv = 1.f / s;
    if (lane == 0) {
        int b = token >> 11;
        int t = token & (SEQ - 1);
#pragma unroll
        for (int e = 0; e < NEXP; ++e)
            scores[((size_t)(b * NEXP + e)) * SEQ + t] = acc[e] * inv;
    }
}

// ------- expert-choice top-k via exact rank (stable, desc), 256 blocks -------
__global__ __launch_bounds__(256)
void topk_kernel(const float* __restrict__ scores, int* __restrict__ sel,
                 float* __restrict__ gate, int* __restrict__ cnt,
                 int* __restrict__ invmap) {
    int be    = blockIdx.x >> 3;
    int chunk = blockIdx.x & 7;
    const float* sc = scores + (size_t)be * SEQ;
    __shared__ float s_sc[SEQ];
    int t = threadIdx.x;
#pragma unroll
    for (int q = 0; q < 8; ++q) s_sc[t + q * 256] = sc[t + q * 256];
    __syncthreads();
    int i = chunk * 256 + t;
    float v = s_sc[i];
    int r = 0;
#pragma unroll 8
    for (int j = 0; j < SEQ; ++j) {
        float u = s_sc[j];
        r += (u > v) || (u == v && j < i);
    }
    if (r < CAPC) {
        sel [(size_t)be * CAPC + r] = i;
        gate[(size_t)be * CAPC + r] = v;
        int b = be >> 3, e = be & 7;
        int tok = b * SEQ + i;
        int p = atomicAdd(cnt + tok, 1);
        invmap[(size_t)tok * 8 + p] = e * RPEX + b * CAPC + r;   // Y row
    }
}

// ---------------- gather: A1 rows (padded) -> bf16 ---------------------------
__global__ __launch_bounds__(256)
void gather_kernel(const float* __restrict__ x, const int* __restrict__ sel,
                   unsigned short* __restrict__ dhi) {
    int gr = blockIdx.x;
    int e  = gr / RPEX;
    int rl = gr - e * RPEX;
    int t  = threadIdx.x;
    size_t dbase = (size_t)gr * DIMD + t * 4;
    if (rl < BATCH * CAPC) {
        int b = rl / CAPC, c = rl - b * CAPC;
        int tok = sel[(size_t)(b * NEXP + e) * CAPC + c];
        float4 v = *reinterpret_cast<const float4*>(x + ((size_t)(b * SEQ + tok)) * DIMD + t * 4);
        ushort4 h;
        h.x = f2bf(v.x); h.y = f2bf(v.y); h.z = f2bf(v.z); h.w = f2bf(v.w);
        *reinterpret_cast<ushort4*>(dhi + dbase) = h;
    } else {
        ushort4 z = {0, 0, 0, 0};
        *reinterpret_cast<ushort4*>(dhi + dbase) = z;
    }
}

// ------ weight transpose of a sub-block: src[k0+kLen][n0+nLen] -> [n][k] bf16 -
__global__ __launch_bounds__(256)
void convT_kernel(const float* __restrict__ src, unsigned short* __restrict__ dhi,
                  int Nsrc, size_t srcEStride, int k0, int n0, int kLen, int nLen) {
    int e = blockIdx.z;
    src += (size_t)e * srcEStride;
    dhi += (size_t)e * kLen * nLen;
    int kb = blockIdx.x * 64, nb = blockIdx.y * 64;
    __shared__ float T[64][65];
    int t = threadIdx.x;
    for (int i = t; i < 1024; i += 256) {
        int r = i >> 4, c4 = (i & 15) * 4;
        float4 v = *reinterpret_cast<const float4*>(
            src + (size_t)(k0 + kb + r) * Nsrc + n0 + nb + c4);
        T[r][c4 + 0] = v.x; T[r][c4 + 1] = v.y; T[r][c4 + 2] = v.z; T[r][c4 + 3] = v.w;
    }
    __syncthreads();
    for (int i = t; i < 1024; i += 256) {
        int n = i >> 4, kc = (i & 15) * 4;
        ushort4 h;
        h.x = f2bf(T[kc + 0][n]); h.y = f2bf(T[kc + 1][n]);
        h.z = f2bf(T[kc + 2][n]); h.w = f2bf(T[kc + 3][n]);
        *reinterpret_cast<ushort4*>(dhi + (size_t)(nb + n) * kLen + kb + kc) = h;
    }
}

// ==== single-pass bf16 MFMA GEMMs: gload_lds + XOR swizzle + 3-buf vmcnt =====
// Tile 128x128, BK=32, 256 thr (4 waves, 64x64 each, 4x4 frags 16x16x32).
// LDS [3 buf][128][32] per matrix (48 KB) -> 3 blocks/CU. One barrier per
// K-step; s_waitcnt vmcnt(4) keeps the NEXT tile's 4 loads in flight across
// the barrier. Swizzle: chunk' = chunk ^ ((row>>1)&3), applied to the GLOBAL
// source on stage and the read column on frag reads (r8/r10 validated:
// SQ_LDS_BANK_CONFLICT == 0). LDA/LDB = row strides (may exceed K extent).

#define GEMM_PRE(Abase, LDA, Bbase, LDB)                                        \
    int t = threadIdx.x;                                                        \
    int l = t & 63, wid = t >> 6;                                               \
    int wr = wid >> 1, wc = wid & 1;                                            \
    int grp = l >> 4, li = l & 15;                                              \
    int fsw  = (grp ^ ((li >> 1) & 3)) * 8;                                     \
    int gsrc = ((l & 3) ^ ((l >> 3) & 3)) * 8;                                  \
    int ra0 = (wid * 2) * 16 + (l >> 2);                                        \
    int ra1 = ra0 + 16;                                                         \
    __shared__ __align__(16) unsigned short As[3][4096];                        \
    __shared__ __align__(16) unsigned short Bs[3][4096];                        \
    int regA = wid * 1024;                                                      \
    const unsigned short* gA0 = (Abase) + (size_t)(bx * 128 + ra0) * (LDA) + gsrc; \
    const unsigned short* gA1 = (Abase) + (size_t)(bx * 128 + ra1) * (LDA) + gsrc; \
    const unsigned short* gB0 = (Bbase) + (size_t)(bn + ra0) * (LDB) + gsrc;    \
    const unsigned short* gB1 = (Bbase) + (size_t)(bn + ra1) * (LDB) + gsrc;    \
    f32x4 acc[4][4];                                                            \
    _Pragma("unroll")                                                           \
    for (int m = 0; m < 4; ++m)                                                 \
        _Pragma("unroll")                                                       \
        for (int n = 0; n < 4; ++n) { f32x4 z = {0.f,0.f,0.f,0.f}; acc[m][n] = z; }

#define STAGE(buf, kt) do {                                                     \
    gl16(gA0 + (kt), &As[buf][regA]);                                           \
    gl16(gA1 + (kt), &As[buf][regA + 512]);                                     \
    gl16(gB0 + (kt), &Bs[buf][regA]);                                           \
    gl16(gB1 + (kt), &Bs[buf][regA + 512]); } while (0)

#define GEMM_LOOP(NT) do {                                                      \
    STAGE(0, 0);                                                                \
    STAGE(1, 32);                                                               \
    int cb = 0;                                                                 \
    for (int tt = 0; tt < (NT); ++tt) {                                         \
        if (tt == (NT) - 1) asm volatile("s_waitcnt vmcnt(0)" ::: "memory");    \
        else                asm volatile("s_waitcnt vmcnt(4)" ::: "memory");    \
        __builtin_amdgcn_s_barrier();                                           \
        int sb = cb + 2; if (sb >= 3) sb -= 3;                                  \
        if (tt + 2 < (NT)) STAGE(sb, (tt + 2) * 32);                            \
        bf16x8 ah[4], bh[4];                                                    \
        const unsigned short* aB = &As[cb][wr * 2048 + li * 32 + fsw];          \
        const unsigned short* bB = &Bs[cb][wc * 2048 + li * 32 + fsw];          \
        ah[0] = *(const bf16x8*)(aB);        ah[1] = *(const bf16x8*)(aB + 512); \
        ah[2] = *(const bf16x8*)(aB + 1024); ah[3] = *(const bf16x8*)(aB + 1536); \
        bh[0] = *(const bf16x8*)(bB);        bh[1] = *(const bf16x8*)(bB + 512); \
        bh[2] = *(const bf16x8*)(bB + 1024); bh[3] = *(const bf16x8*)(bB + 1536); \
        __builtin_amdgcn_s_setprio(1);                                          \
        _Pragma("unroll")                                                       \
        for (int m = 0; m < 4; ++m)                                             \
            _Pragma("unroll")                                                   \
            for (int n = 0; n < 4; ++n)                                         \
                acc[m][n] = __builtin_amdgcn_mfma_f32_16x16x32_bf16(            \
                    ah[m], bh[n], acc[m][n], 0, 0, 0);                          \
        __builtin_amdgcn_s_setprio(0);                                          \
        ++cb; if (cb == 3) cb = 0;                                              \
    } } while (0)

// -------- GEMM1: H[:,chunk] = gelu(A1 @ W1c^T + b1[nbias0+...]), K=1024 ------
__global__ __launch_bounds__(256)
void gemm1_mfma(const unsigned short* __restrict__ Ahi,
                const unsigned short* __restrict__ Whi,
                const float* __restrict__ bias, unsigned short* __restrict__ Hhi,
                size_t wstride, int nbias0, int ldh, int GY) {
    const int K = DIMD;
    int bx, by; swz_grp(GY, bx, by);
    int bn = by * 128;
    int e = bx / TPEX;
    const unsigned short* Bh = Whi + (size_t)e * wstride;

    GEMM_PRE(Ahi, K, Bh, K)
    GEMM_LOOP(K / 32);

    int hr0 = bx * 128 + wr * 64;
    int cb2 = bn + wc * 64;
    const float cc0 = 0.044715f;
    const float cc1 = -2.302118131f;   // -2*0.7978845608*log2(e)
#pragma unroll
    for (int m = 0; m < 4; ++m)
#pragma unroll
        for (int q = 0; q < 4; ++q) {
            int row = hr0 + m * 16 + grp * 4 + q;
#pragma unroll
            for (int n = 0; n < 4; ++n) {
                int col = cb2 + n * 16 + li;
                float v = acc[m][n][q] + bias[(size_t)e * HIDN + nbias0 + col];
                float p = __builtin_fmaf(cc0 * v, v * v, v);
                float g = v * __builtin_amdgcn_rcpf(1.0f + exp2f(cc1 * p));
                Hhi[(size_t)row * ldh + col] = f2bf(g);
            }
        }
}

// ---- GEMM2: split-K=2 -> Y0/Y1 partials (dense rows, no atomics) ------------
// Grid = 8 xcd * 2 ks * 17 bxl * 8 by = 2176. Enumeration check: every
// (bx in 0..135, by in 0..7, ks in 0..1) covered exactly once.
__global__ __launch_bounds__(256)
void gemm2_mfma(const unsigned short* __restrict__ Hh,
                const unsigned short* __restrict__ W2,
                const float* __restrict__ bias, int init,
                const float* __restrict__ gate,
                float* __restrict__ Y0, float* __restrict__ Y1,
                size_t wstride, int lda, int Kb) {
    int xcd = blockIdx.x & 7, pos = blockIdx.x >> 3;   // pos in 0..271
    int ks = pos / (TPEX * 8);                         // 0..1
    int rem = pos - ks * (TPEX * 8);                   // 0..135
    int bxl = rem >> 3, by = rem & 7;                  // 0..16, 0..7
    int bx = xcd * TPEX + bxl;
    int bn = by * 128;
    int e = bx / TPEX;                                 // == xcd
    int rbase_e = (bx - e * TPEX) * 128;
    const unsigned short* Ab = Hh + (size_t)ks * Kb;
    const unsigned short* Bb = W2 + (size_t)e * wstride + (size_t)ks * Kb;

    GEMM_PRE(Ab, lda, Bb, lda)
    GEMM_LOOP(Kb / 32);

    float* Yp = ks ? Y1 : Y0;
    int cb2 = bn + wc * 64;
#pragma unroll
    for (int m = 0; m < 4; ++m)
#pragma unroll
        for (int q = 0; q < 4; ++q) {
            int off = wr * 64 + m * 16 + grp * 4 + q;
            int rloc = rbase_e + off;
            if (rloc < BATCH * CAPC) {
                int b = rloc / CAPC, c = rloc - b * CAPC;
                float g = gate[(size_t)(b * NEXP + e) * CAPC + c];
                size_t grow = (size_t)bx * 128 + off;
#pragma unroll
                for (int n = 0; n < 4; ++n) {
                    int col = cb2 + n * 16 + li;
                    float v = acc[m][n][q];
                    if (ks == 0 && bias) v += bias[(size_t)e * DIMD + col];
                    size_t yo = grow * DIMD + col;
                    if (init) Yp[yo] = g * v;
                    else      Yp[yo] = Yp[yo] + g * v;
                }
            }
        }
}

// ---- combine: out[b,s,:] = sum over <=8 gated (Y0+Y1) rows (no atomics) -----
__global__ __launch_bounds__(64)
void combine_kernel(const float* __restrict__ Y0, const float* __restrict__ Y1,
                    const int* __restrict__ cnt, const int* __restrict__ invmap,
                    float* __restrict__ out) {
    int tok = blockIdx.x;
    int lane = threadIdx.x;
    int n = cnt[tok];
    f32x4 acc[4];
#pragma unroll
    for (int q = 0; q < 4; ++q) { f32x4 z = {0.f, 0.f, 0.f, 0.f}; acc[q] = z; }
#pragma unroll
    for (int j = 0; j < 8; ++j) {
        if (j < n) {
            int row = invmap[(size_t)tok * 8 + j];
            const f32x4* y0 = reinterpret_cast<const f32x4*>(Y0 + (size_t)row * DIMD);
            const f32x4* y1 = reinterpret_cast<const f32x4*>(Y1 + (size_t)row * DIMD);
#pragma unroll
            for (int q = 0; q < 4; ++q) acc[q] += y0[q * 64 + lane] + y1[q * 64 + lane];
        }
    }
    f32x4* op = reinterpret_cast<f32x4*>(out + (size_t)tok * DIMD);
#pragma unroll
    for (int q = 0; q < 4; ++q) op[q * 64 + lane] = acc[q];
}

extern "C" void kernel_launch(void* const* d_in, const int* in_sizes, int n_in,
                              void* d_out, int out_size, void* d_ws, size_t ws_size,
                              hipStream_t stream) {
    (void)in_sizes; (void)n_in; (void)out_size;
    const float* x  = (const float*)d_in[0];
    const float* rw = (const float*)d_in[1];
    const float* w1 = (const float*)d_in[2];
    const float* b1 = (const float*)d_in[3];
    const float* w2 = (const float*)d_in[4];
    const float* b2 = (const float*)d_in[5];
    float* out = (float*)d_out;

    char* ws = (char*)d_ws;
    size_t off = 0;
    auto alloc = [&](size_t bytes) -> char* {
        char* p = ws + off;
        off = (off + bytes + 255) & ~(size_t)255;
        return p;
    };

    float* scores = (float*)alloc((size_t)BATCH * NEXP * SEQ * 4);
    int*   sel    = (int*)  alloc((size_t)BATCH * NEXP * CAPC * 4);
    float* gate   = (float*)alloc((size_t)BATCH * NEXP * CAPC * 4);
    int*   cnt    = (int*)  alloc((size_t)BATCH * SEQ * 4);
    int*   invmap = (int*)  alloc((size_t)BATCH * SEQ * 8 * 4);
    float* Y0     = (float*)alloc((size_t)MTOT * DIMD * 4);
    float* Y1     = (float*)alloc((size_t)MTOT * DIMD * 4);
    size_t common = off;

    // ---- choose N-chunk factor C ----
    const size_t A1B = (size_t)MTOT * DIMD * 2;          // A1 bf16
    int C = 8;
    for (int c = 1; c <= 8; c <<= 1) {
        size_t wc = (size_t)NEXP * (HIDN / c) * DIMD * 2;
        size_t hc = (size_t)MTOT * (HIDN / c) * 2;
        size_t need = common + A1B + 2 * wc + hc + (8u << 20);
        if (need <= ws_size) { C = c; break; }
    }
    const int HN = HIDN / C;           // >=512
    const int nY1 = HN / 128;
    const int GY1 = (nY1 < 8) ? nY1 : 8;

    unsigned short* A1h = (unsigned short*)alloc(A1B);
    size_t WCB = (size_t)NEXP * HN * DIMD * 2;
    size_t HCB = (size_t)MTOT * HN * 2;
    unsigned short* W1h = (unsigned short*)alloc(WCB);
    unsigned short* W2h = (unsigned short*)alloc(WCB);
    unsigned short* Hh  = (unsigned short*)alloc(HCB);

    hipMemsetAsync(cnt, 0, (size_t)BATCH * SEQ * 4, stream);
    router_kernel<<<BATCH * SEQ, 64, 0, stream>>>(x, rw, scores);
    topk_kernel<<<BATCH * NEXP * 8, 256, 0, stream>>>(scores, sel, gate, cnt, invmap);
    gather_kernel<<<MTOT, 256, 0, stream>>>(x, sel, A1h);

    for (int c = 0; c < C; ++c) {
        convT_kernel<<<dim3(DIMD / 64, HN / 64, NEXP), 256, 0, stream>>>(
            w1, W1h, HIDN, (size_t)DIMD * HIDN, 0, c * HN, DIMD, HN);
        gemm1_mfma<<<MTILES * nY1, 256, 0, stream>>>(
            A1h, W1h, b1, Hh, (size_t)HN * DIMD, c * HN, HN, GY1);
        convT_kernel<<<dim3(HN / 64, DIMD / 64, NEXP), 256, 0, stream>>>(
            w2, W2h, DIMD, (size_t)HIDN * DIMD, c * HN, 0, HN, DIMD);
        gemm2_mfma<<<MTILES * 8 * 2, 256, 0, stream>>>(
            Hh, W2h, (c == 0) ? b2 : nullptr, (c == 0) ? 1 : 0, gate, Y0, Y1,
            (size_t)DIMD * HN, HN, HN / 2);
    }
    combine_kernel<<<BATCH * SEQ, 64, 0, stream>>>(Y0, Y1, cnt, invmap, out);
}

// Round 15
// 569.402 us; speedup vs baseline: 1.0902x; 1.0902x over previous
//
#include <hip/hip_runtime.h>
#include <cstdint>

#define DIMD  1024
#define NEXP  8
#define HIDN  4096
#define BATCH 4
#define SEQ   2048
#define CAPC  513                  // int(2048*2.0/8)+1
#define RPEX  2176                 // rows per expert, padded to 17*128
#define TPEX  17                   // 128-row tiles per expert
#define MTOT  (NEXP * RPEX)        // 17408
#define MTILES (MTOT / 128)        // 136

typedef __bf16 bf16x8 __attribute__((ext_vector_type(8)));
typedef float  f32x4  __attribute__((ext_vector_type(4)));

__device__ __forceinline__ unsigned short f2bf(float f) {
    unsigned u = __float_as_uint(f);
    unsigned r = (u + 0x7FFFu + ((u >> 16) & 1u)) >> 16;
    return (unsigned short)r;
}

// async 16B global->LDS (direct DMA). LDS dest = wave-uniform base + lane*16.
__device__ __forceinline__ void gl16(const unsigned short* g, unsigned short* l) {
    __builtin_amdgcn_global_load_lds(
        (const __attribute__((address_space(1))) void*)g,
        (__attribute__((address_space(3))) void*)l, 16, 0, 0);
}

// Within-XCD supercolumn traversal (128-row tiles). Grid = MTILES * nY.
__device__ __forceinline__ void swz_grp(int GY, int& bx, int& by) {
    int xcd = blockIdx.x & 7, pos = blockIdx.x >> 3;
    int tps = TPEX * GY;
    int sc = pos / tps, rem = pos - sc * tps;
    int bxl = rem / GY, byIn = rem - bxl * GY;
    bx = xcd * TPEX + bxl;
    by = sc * GY + byIn;
}

// ---------------- router: scores_t [B][E][S] = softmax over E ----------------
__global__ __launch_bounds__(64)
void router_kernel(const float* __restrict__ x, const float* __restrict__ rw,
                   float* __restrict__ scores) {
    int token = blockIdx.x;
    int lane  = threadIdx.x;
    const float4* xr = reinterpret_cast<const float4*>(x + (size_t)token * DIMD);
    float4 xv[4];
#pragma unroll
    for (int j = 0; j < 4; ++j) xv[j] = xr[lane * 4 + j];
    float acc[NEXP];
#pragma unroll
    for (int e = 0; e < NEXP; ++e) {
        const float4* wr = reinterpret_cast<const float4*>(rw + (size_t)e * DIMD);
        float a = 0.f;
#pragma unroll
        for (int j = 0; j < 4; ++j) {
            float4 wv = wr[lane * 4 + j];
            a += xv[j].x * wv.x; a += xv[j].y * wv.y;
            a += xv[j].z * wv.z; a += xv[j].w * wv.w;
        }
#pragma unroll
        for (int off = 32; off > 0; off >>= 1) a += __shfl_xor(a, off);
        acc[e] = a;
    }
    float m = acc[0];
#pragma unroll
    for (int e = 1; e < NEXP; ++e) m = fmaxf(m, acc[e]);
    float s = 0.f;
#pragma unroll
    for (int e = 0; e < NEXP; ++e) { acc[e] = expf(acc[e] - m); s += acc[e]; }
    float inv = 1.f / s;
    if (lane == 0) {
        int b = token >> 11;
        int t = token & (SEQ - 1);
#pragma unroll
        for (int e = 0; e < NEXP; ++e)
            scores[((size_t)(b * NEXP + e)) * SEQ + t] = acc[e] * inv;
    }
}

// ------ weight transpose body: src[k0+kLen][n0+nLen] -> [n][k] bf16 ----------
// cid decodes (e, k-tile, n-tile); T is 64x65 floats of LDS scratch.
__device__ __forceinline__ void convT_body(const float* __restrict__ src,
        unsigned short* __restrict__ dhi, int Nsrc, size_t srcEStride,
        int k0, int n0, int kLen, int nLen, int cid, float (*T)[65]) {
    int nx = kLen >> 6, ny = nLen >> 6;
    int e = cid / (nx * ny);
    int r2 = cid - e * nx * ny;
    int kb = (r2 % nx) * 64, nb = (r2 / nx) * 64;
    src += (size_t)e * srcEStride;
    dhi += (size_t)e * (size_t)kLen * nLen;
    int t = threadIdx.x;
    for (int i = t; i < 1024; i += 256) {
        int r = i >> 4, c4 = (i & 15) * 4;
        float4 v = *reinterpret_cast<const float4*>(
            src + (size_t)(k0 + kb + r) * Nsrc + n0 + nb + c4);
        T[r][c4 + 0] = v.x; T[r][c4 + 1] = v.y; T[r][c4 + 2] = v.z; T[r][c4 + 3] = v.w;
    }
    __syncthreads();
    for (int i = t; i < 1024; i += 256) {
        int n = i >> 4, kc = (i & 15) * 4;
        ushort4 h;
        h.x = f2bf(T[kc + 0][n]); h.y = f2bf(T[kc + 1][n]);
        h.z = f2bf(T[kc + 2][n]); h.w = f2bf(T[kc + 3][n]);
        *reinterpret_cast<ushort4*>(dhi + (size_t)(nb + n) * kLen + kb + kc) = h;
    }
}

// --- fused: blocks 0..255 = expert-choice top-k (exact rank, stable desc);
//     blocks 256.. = convT of w1 chunk 0. Independent roles, no interaction. --
__global__ __launch_bounds__(256)
void topk_conv1(const float* __restrict__ scores, int* __restrict__ sel,
                float* __restrict__ gate, int* __restrict__ cnt,
                int* __restrict__ invmap,
                const float* __restrict__ csrc, unsigned short* __restrict__ cdst,
                int cNsrc, size_t cEStride, int ck0, int cn0, int ckLen, int cnLen) {
    __shared__ __align__(16) float T[64][65];
    if ((int)blockIdx.x >= 256) {
        convT_body(csrc, cdst, cNsrc, cEStride, ck0, cn0, ckLen, cnLen,
                   blockIdx.x - 256, T);
        return;
    }
    float* s_sc = &T[0][0];                       // 2048 floats fit in T
    int be    = blockIdx.x >> 3;
    int chunk = blockIdx.x & 7;
    const float* sc = scores + (size_t)be * SEQ;
    int t = threadIdx.x;
#pragma unroll
    for (int q = 0; q < 8; ++q) s_sc[t + q * 256] = sc[t + q * 256];
    __syncthreads();
    int i = chunk * 256 + t;
    float v = s_sc[i];
    int r = 0;
#pragma unroll 8
    for (int j = 0; j < SEQ; ++j) {
        float u = s_sc[j];
        r += (u > v) || (u == v && j < i);
    }
    if (r < CAPC) {
        sel [(size_t)be * CAPC + r] = i;
        gate[(size_t)be * CAPC + r] = v;
        int b = be >> 3, e = be & 7;
        int tok = b * SEQ + i;
        int p = atomicAdd(cnt + tok, 1);
        invmap[(size_t)tok * 8 + p] = e * RPEX + b * CAPC + r;   // Y row
    }
}

// ---------------- gather: A1 rows (padded) -> bf16 ---------------------------
__global__ __launch_bounds__(256)
void gather_kernel(const float* __restrict__ x, const int* __restrict__ sel,
                   unsigned short* __restrict__ dhi) {
    int gr = blockIdx.x;
    int e  = gr / RPEX;
    int rl = gr - e * RPEX;
    int t  = threadIdx.x;
    size_t dbase = (size_t)gr * DIMD + t * 4;
    if (rl < BATCH * CAPC) {
        int b = rl / CAPC, c = rl - b * CAPC;
        int tok = sel[(size_t)(b * NEXP + e) * CAPC + c];
        float4 v = *reinterpret_cast<const float4*>(x + ((size_t)(b * SEQ + tok)) * DIMD + t * 4);
        ushort4 h;
        h.x = f2bf(v.x); h.y = f2bf(v.y); h.z = f2bf(v.z); h.w = f2bf(v.w);
        *reinterpret_cast<ushort4*>(dhi + dbase) = h;
    } else {
        ushort4 z = {0, 0, 0, 0};
        *reinterpret_cast<ushort4*>(dhi + dbase) = z;
    }
}

// ==== single-pass bf16 MFMA GEMMs: gload_lds + XOR swizzle + 3-buf vmcnt =====
// Tile 128x128, BK=32, 256 thr (4 waves, 64x64 each, 4x4 frags 16x16x32).
// LDS [3 buf][128][32] per matrix (48 KB) -> 3 blocks/CU. One barrier per
// K-step; s_waitcnt vmcnt(4) keeps the NEXT tile's 4 loads in flight across
// the barrier. Swizzle: chunk' = chunk ^ ((row>>1)&3), applied to the GLOBAL
// source on stage and the read column on frag reads (r8/r10 validated:
// SQ_LDS_BANK_CONFLICT == 0). As/Bs are declared by the KERNEL (so conv-role
// blocks can alias T onto As without doubling LDS).

#define GEMM_PRE(Abase, LDA, Bbase, LDB)                                        \
    int t = threadIdx.x;                                                        \
    int l = t & 63, wid = t >> 6;                                               \
    int wr = wid >> 1, wc = wid & 1;                                            \
    int grp = l >> 4, li = l & 15;                                              \
    int fsw  = (grp ^ ((li >> 1) & 3)) * 8;                                     \
    int gsrc = ((l & 3) ^ ((l >> 3) & 3)) * 8;                                  \
    int ra0 = (wid * 2) * 16 + (l >> 2);                                        \
    int ra1 = ra0 + 16;                                                         \
    int regA = wid * 1024;                                                      \
    const unsigned short* gA0 = (Abase) + (size_t)(bx * 128 + ra0) * (LDA) + gsrc; \
    const unsigned short* gA1 = (Abase) + (size_t)(bx * 128 + ra1) * (LDA) + gsrc; \
    const unsigned short* gB0 = (Bbase) + (size_t)(bn + ra0) * (LDB) + gsrc;    \
    const unsigned short* gB1 = (Bbase) + (size_t)(bn + ra1) * (LDB) + gsrc;    \
    f32x4 acc[4][4];                                                            \
    _Pragma("unroll")                                                           \
    for (int m = 0; m < 4; ++m)                                                 \
        _Pragma("unroll")                                                       \
        for (int n = 0; n < 4; ++n) { f32x4 z = {0.f,0.f,0.f,0.f}; acc[m][n] = z; }

#define STAGE(buf, kt) do {                                                     \
    gl16(gA0 + (kt), &As[buf][regA]);                                           \
    gl16(gA1 + (kt), &As[buf][regA + 512]);                                     \
    gl16(gB0 + (kt), &Bs[buf][regA]);                                           \
    gl16(gB1 + (kt), &Bs[buf][regA + 512]); } while (0)

#define GEMM_LOOP(NT) do {                                                      \
    STAGE(0, 0);                                                                \
    STAGE(1, 32);                                                               \
    int cb = 0;                                                                 \
    for (int tt = 0; tt < (NT); ++tt) {                                         \
        if (tt == (NT) - 1) asm volatile("s_waitcnt vmcnt(0)" ::: "memory");    \
        else                asm volatile("s_waitcnt vmcnt(4)" ::: "memory");    \
        __builtin_amdgcn_s_barrier();                                           \
        int sb = cb + 2; if (sb >= 3) sb -= 3;                                  \
        if (tt + 2 < (NT)) STAGE(sb, (tt + 2) * 32);                            \
        bf16x8 ah[4], bh[4];                                                    \
        const unsigned short* aB = &As[cb][wr * 2048 + li * 32 + fsw];          \
        const unsigned short* bB = &Bs[cb][wc * 2048 + li * 32 + fsw];          \
        ah[0] = *(const bf16x8*)(aB);        ah[1] = *(const bf16x8*)(aB + 512); \
        ah[2] = *(const bf16x8*)(aB + 1024); ah[3] = *(const bf16x8*)(aB + 1536); \
        bh[0] = *(const bf16x8*)(bB);        bh[1] = *(const bf16x8*)(bB + 512); \
        bh[2] = *(const bf16x8*)(bB + 1024); bh[3] = *(const bf16x8*)(bB + 1536); \
        __builtin_amdgcn_s_setprio(1);                                          \
        _Pragma("unroll")                                                       \
        for (int m = 0; m < 4; ++m)                                             \
            _Pragma("unroll")                                                   \
            for (int n = 0; n < 4; ++n)                                         \
                acc[m][n] = __builtin_amdgcn_mfma_f32_16x16x32_bf16(            \
                    ah[m], bh[n], acc[m][n], 0, 0, 0);                          \
        __builtin_amdgcn_s_setprio(0);                                          \
        ++cb; if (cb == 3) cb = 0;                                              \
    } } while (0)

// -- GEMM1 (blocks < nGemm): H = gelu(A1 @ W1c^T + b1); blocks >= nGemm run
//    convT of w2 chunk c (fills gemm1's tail; traffic hides under compute). ---
__global__ __launch_bounds__(256)
void gemm1_mfma(const unsigned short* __restrict__ Ahi,
                const unsigned short* __restrict__ Whi,
                const float* __restrict__ bias, unsigned short* __restrict__ Hhi,
                size_t wstride, int nbias0, int ldh, int GY, int nGemm,
                const float* __restrict__ csrc, unsigned short* __restrict__ cdst,
                int cNsrc, size_t cEStride, int ck0, int cn0, int ckLen, int cnLen) {
    __shared__ __align__(16) unsigned short As[3][4096];
    __shared__ __align__(16) unsigned short Bs[3][4096];
    if ((int)blockIdx.x >= nGemm) {
        convT_body(csrc, cdst, cNsrc, cEStride, ck0, cn0, ckLen, cnLen,
                   blockIdx.x - nGemm, reinterpret_cast<float(*)[65]>(&As[0][0]));
        return;
    }
    const int K = DIMD;
    int bx, by; swz_grp(GY, bx, by);
    int bn = by * 128;
    int e = bx / TPEX;
    const unsigned short* Bh = Whi + (size_t)e * wstride;

    GEMM_PRE(Ahi, K, Bh, K)
    GEMM_LOOP(K / 32);

    int hr0 = bx * 128 + wr * 64;
    int cb2 = bn + wc * 64;
    const float cc0 = 0.044715f;
    const float cc1 = -2.302118131f;   // -2*0.7978845608*log2(e)
#pragma unroll
    for (int m = 0; m < 4; ++m)
#pragma unroll
        for (int q = 0; q < 4; ++q) {
            int row = hr0 + m * 16 + grp * 4 + q;
#pragma unroll
            for (int n = 0; n < 4; ++n) {
                int col = cb2 + n * 16 + li;
                float v = acc[m][n][q] + bias[(size_t)e * HIDN + nbias0 + col];
                float p = __builtin_fmaf(cc0 * v, v * v, v);
                float g = v * __builtin_amdgcn_rcpf(1.0f + exp2f(cc1 * p));
                Hhi[(size_t)row * ldh + col] = f2bf(g);
            }
        }
}

// -- GEMM2 (blocks < nGemm): Y (+)= gate*(Hc @ W2c^T [+ b2]) dense, no atomics;
//    blocks >= nGemm run convT of w1 chunk c+1 (only when C > 1). -------------
__global__ __launch_bounds__(256)
void gemm2_mfma(const unsigned short* __restrict__ Hh,
                const unsigned short* __restrict__ W2,
                const float* __restrict__ bias, const float* __restrict__ gate,
                float* __restrict__ Y, size_t wstride, int K, int GY, int nGemm,
                const float* __restrict__ csrc, unsigned short* __restrict__ cdst,
                int cNsrc, size_t cEStride, int ck0, int cn0, int ckLen, int cnLen) {
    __shared__ __align__(16) unsigned short As[3][4096];
    __shared__ __align__(16) unsigned short Bs[3][4096];
    if ((int)blockIdx.x >= nGemm) {
        convT_body(csrc, cdst, cNsrc, cEStride, ck0, cn0, ckLen, cnLen,
                   blockIdx.x - nGemm, reinterpret_cast<float(*)[65]>(&As[0][0]));
        return;
    }
    int bx, by; swz_grp(GY, bx, by);
    int bn = by * 128;
    int e = bx / TPEX;
    int rbase_e = (bx - e * TPEX) * 128;
    const unsigned short* Bb = W2 + (size_t)e * wstride;

    GEMM_PRE(Hh, K, Bb, K)
    GEMM_LOOP(K / 32);

    int cb2 = bn + wc * 64;
#pragma unroll
    for (int m = 0; m < 4; ++m)
#pragma unroll
        for (int q = 0; q < 4; ++q) {
            int off = wr * 64 + m * 16 + grp * 4 + q;
            int rloc = rbase_e + off;
            if (rloc < BATCH * CAPC) {
                int b = rloc / CAPC, c = rloc - b * CAPC;
                float g = gate[(size_t)(b * NEXP + e) * CAPC + c];
                size_t grow = (size_t)bx * 128 + off;
#pragma unroll
                for (int n = 0; n < 4; ++n) {
                    int col = cb2 + n * 16 + li;
                    float v = acc[m][n][q];
                    size_t yo = grow * DIMD + col;
                    if (bias) Y[yo] = g * (v + bias[(size_t)e * DIMD + col]);
                    else      Y[yo] = Y[yo] + g * v;
                }
            }
        }
}

// -------- combine: out[b,s,:] = sum over <=8 gated Y rows (no atomics) -------
__global__ __launch_bounds__(64)
void combine_kernel(const float* __restrict__ Y, const int* __restrict__ cnt,
                    const int* __restrict__ invmap, float* __restrict__ out) {
    int tok = blockIdx.x;
    int lane = threadIdx.x;
    int n = cnt[tok];
    f32x4 acc[4];
#pragma unroll
    for (int q = 0; q < 4; ++q) { f32x4 z = {0.f, 0.f, 0.f, 0.f}; acc[q] = z; }
#pragma unroll
    for (int j = 0; j < 8; ++j) {
        if (j < n) {
            int row = invmap[(size_t)tok * 8 + j];
            const f32x4* yr = reinterpret_cast<const f32x4*>(Y + (size_t)row * DIMD);
#pragma unroll
            for (int q = 0; q < 4; ++q) acc[q] += yr[q * 64 + lane];
        }
    }
    f32x4* op = reinterpret_cast<f32x4*>(out + (size_t)tok * DIMD);
#pragma unroll
    for (int q = 0; q < 4; ++q) op[q * 64 + lane] = acc[q];
}

extern "C" void kernel_launch(void* const* d_in, const int* in_sizes, int n_in,
                              void* d_out, int out_size, void* d_ws, size_t ws_size,
                              hipStream_t stream) {
    (void)in_sizes; (void)n_in; (void)out_size;
    const float* x  = (const float*)d_in[0];
    const float* rw = (const float*)d_in[1];
    const float* w1 = (const float*)d_in[2];
    const float* b1 = (const float*)d_in[3];
    const float* w2 = (const float*)d_in[4];
    const float* b2 = (const float*)d_in[5];
    float* out = (float*)d_out;

    char* ws = (char*)d_ws;
    size_t off = 0;
    auto alloc = [&](size_t bytes) -> char* {
        char* p = ws + off;
        off = (off + bytes + 255) & ~(size_t)255;
        return p;
    };

    float* scores = (float*)alloc((size_t)BATCH * NEXP * SEQ * 4);
    int*   sel    = (int*)  alloc((size_t)BATCH * NEXP * CAPC * 4);
    float* gate   = (float*)alloc((size_t)BATCH * NEXP * CAPC * 4);
    int*   cnt    = (int*)  alloc((size_t)BATCH * SEQ * 4);
    int*   invmap = (int*)  alloc((size_t)BATCH * SEQ * 8 * 4);
    float* Y      = (float*)alloc((size_t)MTOT * DIMD * 4);
    size_t common = off;

    // ---- choose N-chunk factor C ----
    const size_t A1B = (size_t)MTOT * DIMD * 2;          // A1 bf16
    int C = 8;
    for (int c = 1; c <= 8; c <<= 1) {
        size_t wc = (size_t)NEXP * (HIDN / c) * DIMD * 2;
        size_t hc = (size_t)MTOT * (HIDN / c) * 2;
        size_t need = common + A1B + 2 * wc + hc + (8u << 20);
        if (need <= ws_size) { C = c; break; }
    }
    const int HN = HIDN / C;           // >=512
    const int nY1 = HN / 128;
    const int GY1 = (nY1 < 8) ? nY1 : 8;

    unsigned short* A1h = (unsigned short*)alloc(A1B);
    size_t WCB = (size_t)NEXP * HN * DIMD * 2;
    size_t HCB = (size_t)MTOT * HN * 2;
    unsigned short* W1h = (unsigned short*)alloc(WCB);
    unsigned short* W2h = (unsigned short*)alloc(WCB);
    unsigned short* Hh  = (unsigned short*)alloc(HCB);

    const int nCv1 = (DIMD / 64) * (HN / 64) * NEXP;     // w1-chunk conv blocks
    const int nCv2 = (HN / 64) * (DIMD / 64) * NEXP;     // w2-chunk conv blocks

    hipMemsetAsync(cnt, 0, (size_t)BATCH * SEQ * 4, stream);
    router_kernel<<<BATCH * SEQ, 64, 0, stream>>>(x, rw, scores);
    // topk (256 blocks) runs concurrently with convT of w1 chunk 0
    topk_conv1<<<256 + nCv1, 256, 0, stream>>>(
        scores, sel, gate, cnt, invmap,
        w1, W1h, HIDN, (size_t)DIMD * HIDN, 0, 0, DIMD, HN);
    gather_kernel<<<MTOT, 256, 0, stream>>>(x, sel, A1h);

    for (int c = 0; c < C; ++c) {
        int G1 = MTILES * nY1;
        gemm1_mfma<<<G1 + nCv2, 256, 0, stream>>>(
            A1h, W1h, b1, Hh, (size_t)HN * DIMD, c * HN, HN, GY1, G1,
            w2, W2h, DIMD, (size_t)HIDN * DIMD, c * HN, 0, HN, DIMD);
        int G2 = MTILES * (DIMD / 128);
        int more = (c + 1 < C) ? nCv1 : 0;
        gemm2_mfma<<<G2 + more, 256, 0, stream>>>(
            Hh, W2h, (c == 0) ? b2 : nullptr, gate, Y,
            (size_t)DIMD * HN, HN, 4, G2,
            w1, W1h, HIDN, (size_t)DIMD * HIDN, 0, (c + 1) * HN, DIMD, HN);
    }
    combine_kernel<<<BATCH * SEQ, 64, 0, stream>>>(Y, cnt, invmap, out);
}